// Round 9
// baseline (318.915 us; speedup 1.0000x reference)
//
#include <hip/hip_runtime.h>
#include <math.h>

#define NN   5000
#define DEG  16
#define S    17
#define T    10
#define MN   10
#define D    128
#define NOUT 3
#define NSK  5

#define WPB   2            // waves per block = templates per block (main)
#define BLOCK (WPB * 64)
#define TILE_N 32          // nodes per block in the Mp GEMM
#define NEG   -3.0e38f

__device__ __forceinline__ float fast_rcp(float x) { return __builtin_amdgcn_rcpf(x); }

// DPP row_ror:k — pure-VALU cross-lane within each 16-lane row.
template <int CTRL>
__device__ __forceinline__ float dpp_movf(float v) {
    return __int_as_float(__builtin_amdgcn_update_dpp(
        0, __float_as_int(v), CTRL, 0xF, 0xF, true));
}
__device__ __forceinline__ int dpp_movi(int v) {
    return __builtin_amdgcn_update_dpp(0, v, 0x121, 0xF, 0xF, true);
}
__device__ __forceinline__ float rowsum16(float v) {
    v += dpp_movf<0x121>(v);
    v += dpp_movf<0x122>(v);
    v += dpp_movf<0x124>(v);
    v += dpp_movf<0x128>(v);
    return v;
}
__device__ __forceinline__ float rowmax16(float v) {
    v = fmaxf(v, dpp_movf<0x121>(v));
    v = fmaxf(v, dpp_movf<0x122>(v));
    v = fmaxf(v, dpp_movf<0x124>(v));
    v = fmaxf(v, dpp_movf<0x128>(v));
    return v;
}

// ---------------- P1: adjacency masks (+ sqF2 in the extra block) ----------------
// Round-9: round 8's monolithic pre-kernel took ~73us (25% of wall) because
// its dot phase ran 100/320 threads on serial 128-FMA dots, once per node.
// P1 keeps only the cheap mask build; the GEMM moves to tiled P2.
__global__ __launch_bounds__(320) void ltfgw_mask(
    const int*   __restrict__ edge,     // [2, N*DEG]
    const float* __restrict__ F2,       // [100, D] flat
    unsigned*    __restrict__ wsMask,   // [N, 17]
    float*       __restrict__ wsSqF2)   // [100]
{
    const int n   = blockIdx.x;
    const int tid = threadIdx.x;
    const int* dst = edge + NN * DEG;

    if (n == NN) {                       // sqF2[c] = ||F2f[c]||^2
        if (tid < T * MN) {
            const float4* fr = (const float4*)(F2 + (size_t)tid * D);
            float acc = 0.f;
            #pragma unroll 8
            for (int i = 0; i < D / 4; ++i) {
                float4 f = fr[i];
                acc += f.x*f.x + f.y*f.y + f.z*f.z + f.w*f.w;
            }
            wsSqF2[tid] = acc;
        }
        return;
    }

    __shared__ int      loc[S];
    __shared__ int      neigh[S][DEG];
    __shared__ unsigned cm[S];

    if (tid < S) { loc[tid] = (tid == 0) ? n : dst[n * DEG + tid - 1]; cm[tid] = 0u; }
    __syncthreads();
    if (tid < S * DEG) neigh[tid >> 4][tid & 15] = dst[loc[tid >> 4] * DEG + (tid & 15)];
    __syncthreads();
    if (tid < S * S) {
        int a = tid / S, b = tid % S;
        int la = loc[a], lb = loc[b];
        bool adj = false;
        #pragma unroll
        for (int k = 0; k < DEG; ++k) adj = adj | (neigh[a][k] == lb) | (neigh[b][k] == la);
        if (a != b && adj) atomicOr(&cm[a], 1u << b);
    }
    __syncthreads();
    if (tid < S) wsMask[n * S + tid] = cm[tid];
}

// ---------------- P2: Mp2[n,c] = -10*(1-alpha)*(||x[n]||^2 - 2 x[n].F2[c] + ||F2[c]||^2)
// Tiled GEMM: 32 nodes x 100 cols per 256-thread block, x staged in LDS
// ([32][132] pad -> the 8 node-groups hit distinct banks), F2 L1-resident.
// Every thread busy with 12-13 dot-accumulators; xsq folded in (each thread
// accumulates its own ||x||^2 alongside, +4 FMA/chunk). sqF2 + the -10*(1-a)
// scale folded here shave ~15 inst/lane off the main kernel's lkP setup.
__global__ __launch_bounds__(256) void ltfgw_mp(
    const float* __restrict__ x,        // [N, D]
    const float* __restrict__ F2,       // [100, D]
    const float* __restrict__ alpha0,   // [1]
    const float* __restrict__ wsSqF2,   // [100]
    float*       __restrict__ wsMp2)    // [N, 100]
{
    const int n0  = blockIdx.x * TILE_N;
    const int tid = threadIdx.x;

    __shared__ float xl[TILE_N][132];   // pad 132: node stride 528B -> distinct banks

    for (int i = tid; i < TILE_N * (D / 4); i += 256) {
        int nl = i >> 5, d4 = i & 31;
        int n  = n0 + nl;
        float4 v = (n < NN) ? ((const float4*)(x + (size_t)n * D))[d4]
                            : make_float4(0.f, 0.f, 0.f, 0.f);
        *(float4*)&xl[nl][d4 * 4] = v;
    }
    __syncthreads();

    const int nl    = tid >> 3;
    const int cslot = tid & 7;
    const int n     = n0 + nl;

    float acc[13];
    #pragma unroll
    for (int k = 0; k < 13; ++k) acc[k] = 0.f;
    float xacc = 0.f;

    for (int d4 = 0; d4 < D / 4; ++d4) {
        float4 xv = *(const float4*)&xl[nl][d4 * 4];
        xacc += xv.x*xv.x + xv.y*xv.y + xv.z*xv.z + xv.w*xv.w;
        #pragma unroll
        for (int k = 0; k < 13; ++k) {
            int c = cslot + 8 * k;
            if (c < T * MN) {
                float4 f = ((const float4*)(F2 + (size_t)c * D))[d4];
                acc[k] += f.x*xv.x + f.y*xv.y + f.z*xv.z + f.w*xv.w;
            }
        }
    }

    const float alpha = 1.f / (1.f + __expf(-alpha0[0]));
    const float sc    = -10.f * (1.f - alpha);
    if (n < NN) {
        #pragma unroll
        for (int k = 0; k < 13; ++k) {
            int c = cslot + 8 * k;
            if (c < T * MN)
                wsMp2[n * (T * MN) + c] = sc * (xacc - 2.f * acc[k] + wsSqF2[c]);
        }
    }
}

// ---------------- Main: one wave = one (node, template) OT problem ----------------
// Lane = q*16+m; lane owns rows s = q+4r (r=0..3) + row 16 (replicated
// across quads, counted once). All width-16 reductions via DPP. H = G*C2^T
// via DPP rotation (C2rot probed with the same DPP op -> direction-proof).
// outer-0 tens analytic (G0 = p q^T). Sinkhorn exp-domain with per-outer
// rowmax stabilization (exact vs reference log-domain; v_ masked to 0 on
// inactive lanes -> round-4 NaN lesson). lkP = Mp2[lr,c] - 20a*cC with Mp2
// pre-scaled in P2. __launch_bounds__: block size ONLY (rounds 2-3 lesson).
__global__ __launch_bounds__(BLOCK) void ltfgw_wave(
    const int*      __restrict__ edge,     // [2, N*DEG]
    const float*    __restrict__ tmpl,     // [T, MN, MN]
    const float*    __restrict__ q0,       // [T, MN]
    const float*    __restrict__ alpha0,   // [1]
    const float*    __restrict__ wsMp2,    // [N, 100]
    const unsigned* __restrict__ wsMask,   // [N, 17]
    float*          __restrict__ out)      // [N, T]
{
    const int blk  = blockIdx.x;
    const int n    = blk / 5;
    const int tp   = blk % 5;
    const int tid  = threadIdx.x;
    const int w    = tid >> 6;
    const int t    = tp * 2 + w;
    const int lane = tid & 63;
    const int q    = lane >> 4;
    const int m    = lane & 15;
    const bool act = (m < MN);
    const int mc   = act ? m : (MN - 1);

    __shared__ float C2l[WPB][MN][17];     // stride 17: conflict-free

    const int* dst = edge + NN * DEG;

    // q = softmax(q0[t]) via DPP row reduction (all lanes)
    float vq = q0[t * MN + mc];
    float zq = act ? vq : NEG;
    float mq = rowmax16(zq);
    float sq = rowsum16(__expf(zq - mq));     // inactive: exp(NEG-mq)=0
    const float qm = __expf(vq - (mq + __logf(sq)));   // valid on act lanes
    // C2 = softmax(tmpl, axis=1): active lane m of quad 0 does column m
    if (act && q == 0) {
        float v[MN]; float cm = NEG;
        #pragma unroll
        for (int i = 0; i < MN; ++i) { v[i] = tmpl[t * MN * MN + i * MN + m]; cm = fmaxf(cm, v[i]); }
        float ssum = 0.f;
        #pragma unroll
        for (int i = 0; i < MN; ++i) { v[i] = __expf(v[i] - cm); ssum += v[i]; }
        float inv = 1.f / ssum;
        #pragma unroll
        for (int i = 0; i < MN; ++i) C2l[w][i][m] = v[i] * inv;
    }

    // per-row gathers (L2-resident ws): rows sr[r] = q+4r, clamp 16
    int sr[5];
    #pragma unroll
    for (int r = 0; r < 5; ++r) { int s0 = q + 4 * r; sr[r] = (s0 > 16) ? 16 : s0; }
    unsigned msk[5]; float npop[5]; float Mp2g[5];
    const int cidx = t * MN + mc;
    #pragma unroll
    for (int r = 0; r < 5; ++r) {
        int lr   = (sr[r] == 0) ? n : dst[n * DEG + sr[r] - 1];
        msk[r]   = wsMask[n * S + sr[r]];
        npop[r]  = (float)__popc(msk[r]);
        Mp2g[r]  = wsMp2[lr * (T * MN) + cidx];
    }

    __syncthreads();   // C2l ready

    // C2rot[i] = C2[mc][sigma^i(m)] — sigma probed with the same DPP op,
    // so the rotated-G dot product below is rotation-direction-proof.
    float C2rot[16];
    {
        int li = m;
        #pragma unroll
        for (int i = 0; i < 16; ++i) {
            C2rot[i] = (li < MN) ? C2l[w][mc][li] : 0.f;
            if (i < 15) li = dpp_movi(li);
        }
    }
    // hC2 = sum_j C2[mc][j]^2 q[j]; qC2m = sum_j C2[mc][j] q[j]
    float hC2 = 0.f, qC2m = 0.f;
    {
        float qrot = qm;
        #pragma unroll
        for (int i = 0; i < 16; ++i) {
            float cq = C2rot[i] * qrot;
            qC2m += cq;
            hC2  = fmaf(C2rot[i], cq, hC2);
            if (i < 15) qrot = dpp_movf<0x121>(qrot);
        }
    }

    const float alpha = 1.f / (1.f + __expf(-alpha0[0]));
    const float p_    = 1.f / (float)S;
    const float fa4   = 40.f * alpha;         // logK = lkP + 40*alpha*tens
    const float c20a  = 20.f * alpha;
    const float qop   = qm * (float)S;        // q/p for folded v-update

    float lkP[5];
    #pragma unroll
    for (int r = 0; r < 5; ++r) {
        float cC = fmaf(npop[r], p_, hC2);    // hC1 + hC2, hC1 = popc/S
        lkP[r] = Mp2g[r] - c20a * cC;         // = -10*(oma*M + 2a*cC)
    }

    // outer 0 analytic: G0 = p q^T => tens0[r] = p * qC2m * popc(msk[r])
    float tens[5], Kt[5], ub[5], v_, G[5];
    {
        float pq = p_ * qC2m;
        #pragma unroll
        for (int r = 0; r < 5; ++r) tens[r] = pq * npop[r];
    }

    for (int o = 1; o <= NOUT; ++o) {
        // K~ = exp(logK - rowmax) (rowmax via DPP)
        #pragma unroll
        for (int r = 0; r < 5; ++r) {
            float lk = fmaf(fa4, tens[r], lkP[r]);
            float rm = rowmax16(act ? lk : NEG);
            Kt[r] = act ? __expf(lk - rm) : 0.f;
        }
        // folded exp-domain Sinkhorn: û = rcp(K~ v); v = (Sq)*rcp(K~^T û)
        v_ = act ? 1.f : 0.f;
        #pragma unroll
        for (int it = 0; it < NSK; ++it) {
            #pragma unroll
            for (int r = 0; r < 5; ++r)
                ub[r] = fast_rcp(rowsum16(Kt[r] * v_));
            float cs = Kt[0]*ub[0] + Kt[1]*ub[1] + Kt[2]*ub[2] + Kt[3]*ub[3];
            cs += (q == 0) ? Kt[4]*ub[4] : 0.f;   // row 16 counted once
            cs += __shfl_xor(cs, 16, 64);
            cs += __shfl_xor(cs, 32, 64);
            v_ = act ? (qop * fast_rcp(cs)) : 0.f; // mask: rcp(0)=inf -> NaN
        }
        float pv = p_ * v_;
        #pragma unroll
        for (int r = 0; r < 5; ++r) G[r] = Kt[r] * ub[r] * pv;

        // H[own rows][m] = sum_k G[s][k]*C2[m][k] via DPP rotation (VALU-only)
        float H[5];
        #pragma unroll
        for (int r = 0; r < 5; ++r) {
            float h = 0.f, Gr = G[r];
            #pragma unroll
            for (int i = 0; i < 16; ++i) {
                h = fmaf(Gr, C2rot[i], h);
                if (i < 15) Gr = dpp_movf<0x121>(Gr);
            }
            H[r] = h;
        }
        // tens[s][m] = sum_{j in mask} H[j][m]
        #pragma unroll
        for (int r = 0; r < 5; ++r) tens[r] = 0.f;
        #pragma unroll
        for (int j = 0; j < 16; ++j) {
            float hj = __shfl(H[j >> 2], ((j & 3) << 4) + m, 64);
            #pragma unroll
            for (int r = 0; r < 5; ++r) tens[r] += ((msk[r] >> j) & 1u) ? hj : 0.f;
        }
        {
            float hj = H[4];   // row 16: replicated locally in every quad
            #pragma unroll
            for (int r = 0; r < 5; ++r) tens[r] += ((msk[r] >> 16) & 1u) ? hj : 0.f;
        }
    }

    // dist = sum G * (-0.1*lkP - a*cC - 2a*tens)
    float val = 0.f;
    #pragma unroll
    for (int r = 0; r < 5; ++r) {
        float cC = fmaf(npop[r], p_, hC2);
        float integ = -0.1f * lkP[r] - alpha * cC - 2.f * alpha * tens[r];
        bool valid = act && (r < 4 || q == 0);
        val += valid ? G[r] * integ : 0.f;
    }
    val = rowsum16(val);
    val += __shfl_xor(val, 16, 64);
    val += __shfl_xor(val, 32, 64);
    if (lane == 0) out[n * T + t] = val;
}

extern "C" void kernel_launch(void* const* d_in, const int* in_sizes, int n_in,
                              void* d_out, int out_size, void* d_ws, size_t ws_size,
                              hipStream_t stream) {
    const float* x      = (const float*)d_in[0];
    const int*   edge   = (const int*)  d_in[1];
    const float* tmpl   = (const float*)d_in[2];
    const float* F2     = (const float*)d_in[3];
    const float* q0     = (const float*)d_in[4];
    const float* alpha0 = (const float*)d_in[5];
    float*       out    = (float*)d_out;

    // ws layout: Mp2 [N*100] f32 | masks [N*17] u32 | sqF2 [100] f32 (~2.34 MB)
    float*    wsMp2  = (float*)d_ws;
    unsigned* wsMask = (unsigned*)((char*)d_ws + (size_t)NN * T * MN * 4);
    float*    wsSqF2 = (float*)((char*)d_ws + (size_t)NN * T * MN * 4 + (size_t)NN * S * 4);

    hipLaunchKernelGGL(ltfgw_mask, dim3(NN + 1), dim3(320), 0, stream,
                       edge, F2, wsMask, wsSqF2);
    hipLaunchKernelGGL(ltfgw_mp, dim3((NN + TILE_N - 1) / TILE_N), dim3(256), 0, stream,
                       x, F2, alpha0, wsSqF2, wsMp2);
    hipLaunchKernelGGL(ltfgw_wave, dim3(NN * 5), dim3(BLOCK), 0, stream,
                       edge, tmpl, q0, alpha0, wsMp2, wsMask, out);
}

// Round 10
// 310.120 us; speedup vs baseline: 1.0284x; 1.0284x over previous
//
#include <hip/hip_runtime.h>
#include <math.h>

#define NN   5000
#define DEG  16
#define S    17
#define T    10
#define MN   10
#define D    128
#define NOUT 3
#define NSK  5

#define WPB   2            // waves per block = templates per block (main)
#define BLOCK (WPB * 64)
#define TILE_N 16          // nodes per block in the Mp GEMM
#define NEG   -3.0e38f

__device__ __forceinline__ float fast_rcp(float x) { return __builtin_amdgcn_rcpf(x); }

// DPP row_ror:k — pure-VALU cross-lane within each 16-lane row.
template <int CTRL>
__device__ __forceinline__ float dpp_movf(float v) {
    return __int_as_float(__builtin_amdgcn_update_dpp(
        0, __float_as_int(v), CTRL, 0xF, 0xF, true));
}
__device__ __forceinline__ int dpp_movi(int v) {
    return __builtin_amdgcn_update_dpp(0, v, 0x121, 0xF, 0xF, true);
}
__device__ __forceinline__ float rowsum16(float v) {
    v += dpp_movf<0x121>(v);
    v += dpp_movf<0x122>(v);
    v += dpp_movf<0x124>(v);
    v += dpp_movf<0x128>(v);
    return v;
}
__device__ __forceinline__ float rowmax16(float v) {
    v = fmaxf(v, dpp_movf<0x121>(v));
    v = fmaxf(v, dpp_movf<0x122>(v));
    v = fmaxf(v, dpp_movf<0x124>(v));
    v = fmaxf(v, dpp_movf<0x128>(v));
    return v;
}

// ---------------- P1: adjacency masks, one WAVE per node ----------------
// Round-10: round 9 proved the block-per-node mask kernel costs ~65us by
// itself (round-8 pre minus dots on the same grid). Rebuild: no barriers,
// no LDS, no partial-wave tails. Lane = a*4+j holds neigh[a][4j..4j+3];
// B[a] (one-direction adjacency) via 17 readlane-compares; row 16 + the
// symmetrization B|B^T via ballots; diag cleared per reference (1-eye).
__global__ __launch_bounds__(256) void ltfgw_mask(
    const int* __restrict__ edge,      // [2, N*DEG]
    unsigned*  __restrict__ wsMask)    // [N, 17]
{
    const int wid  = blockIdx.x * 4 + (threadIdx.x >> 6);
    const int lane = threadIdx.x & 63;
    if (wid >= NN) return;
    const int n = wid;
    const int* dst = edge + NN * DEG;

    const int a = lane >> 2;           // row 0..15
    const int j = lane & 3;            // 4-neighbor chunk

    int locv = 0;                      // lane l<17 holds loc[l]
    if (lane < S) locv = (lane == 0) ? n : dst[n * DEG + lane - 1];
    int loca  = (a == 0) ? n : dst[n * DEG + a - 1];
    int loc16 = dst[n * DEG + DEG - 1];

    const int4* nbp = (const int4*)(dst + (size_t)loca * DEG);
    int4 nb   = nbp[j];
    int  nb16 = (lane < DEG) ? dst[(size_t)loc16 * DEG + lane] : -1;

    unsigned bits = 0, B16 = 0;
    #pragma unroll
    for (int b = 0; b < S; ++b) {
        int lb = __shfl(locv, b, 64);  // literal lane -> v_readlane (sgpr)
        bool hit = (nb.x == lb) | (nb.y == lb) | (nb.z == lb) | (nb.w == lb);
        bits |= hit ? (1u << b) : 0u;
        if (__ballot((lane < DEG) && (nb16 == lb))) B16 |= (1u << b);
    }
    // OR the 4 chunk lanes of each row
    bits |= __shfl_xor(bits, 1, 4);
    bits |= __shfl_xor(bits, 2, 4);

    // lane l<17 holds full B row l
    unsigned g  = __shfl(bits, (lane & 15) * 4, 64);
    unsigned Bl = (lane == 16) ? B16 : g;
    if (lane > 16) Bl = 0;

    // B^T[l] = low-17 bits of ballot_c at c==l (bit b of bal_l = B[b] bit l)
    unsigned tsel = 0;
    #pragma unroll
    for (int c = 0; c < S; ++c) {
        unsigned long long bal = __ballot((Bl >> c) & 1u);
        unsigned lo = (unsigned)(bal & 0x1FFFFull);
        tsel = (lane == c) ? lo : tsel;
    }

    unsigned maskv = ((Bl | tsel) & ~(1u << lane)) & 0x1FFFFu;
    if (lane < S) wsMask[n * S + lane] = maskv;
}

// ---------------- P2: Mp2[n,c] = -10*(1-a)*(||x[n]||^2 - 2 x[n].F2[c] + ||F2[c]||^2)
// Tiled: 16 nodes x 100 cols per 256-thread block (313 blocks). x staged in
// LDS; F2 L1-resident; sqF2 accumulated inline (facc) — no side-channel
// producer. The -10*(1-a) scale folded here (main kernel reads Mp2 directly).
__global__ __launch_bounds__(256) void ltfgw_mp(
    const float* __restrict__ x,        // [N, D]
    const float* __restrict__ F2,       // [100, D]
    const float* __restrict__ alpha0,   // [1]
    float*       __restrict__ wsMp2)    // [N, 100]
{
    const int n0  = blockIdx.x * TILE_N;
    const int tid = threadIdx.x;

    __shared__ float xl[TILE_N][132];   // pad -> distinct banks per node row

    for (int i = tid; i < TILE_N * (D / 4); i += 256) {
        int nl = i >> 5, d4 = i & 31;
        int n  = n0 + nl;
        float4 v = (n < NN) ? ((const float4*)(x + (size_t)n * D))[d4]
                            : make_float4(0.f, 0.f, 0.f, 0.f);
        *(float4*)&xl[nl][d4 * 4] = v;
    }
    __syncthreads();

    const int nl    = tid >> 4;         // 16 nodes
    const int cslot = tid & 15;         // 16 col-slots, 7 cols each
    const int n     = n0 + nl;

    float acc[7], facc[7];
    #pragma unroll
    for (int k = 0; k < 7; ++k) { acc[k] = 0.f; facc[k] = 0.f; }
    float xacc = 0.f;

    for (int d4 = 0; d4 < D / 4; ++d4) {
        float4 xv = *(const float4*)&xl[nl][d4 * 4];
        xacc += xv.x*xv.x + xv.y*xv.y + xv.z*xv.z + xv.w*xv.w;
        #pragma unroll
        for (int k = 0; k < 7; ++k) {
            int c = cslot + 16 * k;
            if (c < T * MN) {
                float4 f = ((const float4*)(F2 + (size_t)c * D))[d4];
                acc[k]  += f.x*xv.x + f.y*xv.y + f.z*xv.z + f.w*xv.w;
                facc[k] += f.x*f.x + f.y*f.y + f.z*f.z + f.w*f.w;
            }
        }
    }

    const float alpha = 1.f / (1.f + __expf(-alpha0[0]));
    const float sc    = -10.f * (1.f - alpha);
    if (n < NN) {
        #pragma unroll
        for (int k = 0; k < 7; ++k) {
            int c = cslot + 16 * k;
            if (c < T * MN)
                wsMp2[n * (T * MN) + c] = sc * (xacc - 2.f * acc[k] + facc[k]);
        }
    }
}

// ---------------- Main: one wave = one (node, template) OT problem ----------------
// (unchanged from round 9: 221us, VALU-issue-bound, VALUBusy ~107%)
// Lane = q*16+m; lane owns rows s = q+4r (r=0..3) + row 16 (replicated
// across quads, counted once). All width-16 reductions via DPP. H = G*C2^T
// via DPP rotation (C2rot probed with the same DPP op -> direction-proof).
// outer-0 tens analytic (G0 = p q^T). Sinkhorn exp-domain with per-outer
// rowmax stabilization; v_ masked on inactive lanes (round-4 NaN lesson).
// __launch_bounds__: block size ONLY (rounds 2-3: min-waves hint => spills).
__global__ __launch_bounds__(BLOCK) void ltfgw_wave(
    const int*      __restrict__ edge,     // [2, N*DEG]
    const float*    __restrict__ tmpl,     // [T, MN, MN]
    const float*    __restrict__ q0,       // [T, MN]
    const float*    __restrict__ alpha0,   // [1]
    const float*    __restrict__ wsMp2,    // [N, 100]
    const unsigned* __restrict__ wsMask,   // [N, 17]
    float*          __restrict__ out)      // [N, T]
{
    const int blk  = blockIdx.x;
    const int n    = blk / 5;
    const int tp   = blk % 5;
    const int tid  = threadIdx.x;
    const int w    = tid >> 6;
    const int t    = tp * 2 + w;
    const int lane = tid & 63;
    const int q    = lane >> 4;
    const int m    = lane & 15;
    const bool act = (m < MN);
    const int mc   = act ? m : (MN - 1);

    __shared__ float C2l[WPB][MN][17];     // stride 17: conflict-free

    const int* dst = edge + NN * DEG;

    // q = softmax(q0[t]) via DPP row reduction (all lanes)
    float vq = q0[t * MN + mc];
    float zq = act ? vq : NEG;
    float mq = rowmax16(zq);
    float sq = rowsum16(__expf(zq - mq));     // inactive: exp(NEG-mq)=0
    const float qm = __expf(vq - (mq + __logf(sq)));   // valid on act lanes
    // C2 = softmax(tmpl, axis=1): active lane m of quad 0 does column m
    if (act && q == 0) {
        float v[MN]; float cm = NEG;
        #pragma unroll
        for (int i = 0; i < MN; ++i) { v[i] = tmpl[t * MN * MN + i * MN + m]; cm = fmaxf(cm, v[i]); }
        float ssum = 0.f;
        #pragma unroll
        for (int i = 0; i < MN; ++i) { v[i] = __expf(v[i] - cm); ssum += v[i]; }
        float inv = 1.f / ssum;
        #pragma unroll
        for (int i = 0; i < MN; ++i) C2l[w][i][m] = v[i] * inv;
    }

    // per-row gathers (L2-resident ws): rows sr[r] = q+4r, clamp 16
    int sr[5];
    #pragma unroll
    for (int r = 0; r < 5; ++r) { int s0 = q + 4 * r; sr[r] = (s0 > 16) ? 16 : s0; }
    unsigned msk[5]; float npop[5]; float Mp2g[5];
    const int cidx = t * MN + mc;
    #pragma unroll
    for (int r = 0; r < 5; ++r) {
        int lr   = (sr[r] == 0) ? n : dst[n * DEG + sr[r] - 1];
        msk[r]   = wsMask[n * S + sr[r]];
        npop[r]  = (float)__popc(msk[r]);
        Mp2g[r]  = wsMp2[lr * (T * MN) + cidx];
    }

    __syncthreads();   // C2l ready

    // C2rot[i] = C2[mc][sigma^i(m)] — sigma probed with the same DPP op,
    // so the rotated-G dot product below is rotation-direction-proof.
    float C2rot[16];
    {
        int li = m;
        #pragma unroll
        for (int i = 0; i < 16; ++i) {
            C2rot[i] = (li < MN) ? C2l[w][mc][li] : 0.f;
            if (i < 15) li = dpp_movi(li);
        }
    }
    // hC2 = sum_j C2[mc][j]^2 q[j]; qC2m = sum_j C2[mc][j] q[j]
    float hC2 = 0.f, qC2m = 0.f;
    {
        float qrot = qm;
        #pragma unroll
        for (int i = 0; i < 16; ++i) {
            float cq = C2rot[i] * qrot;
            qC2m += cq;
            hC2  = fmaf(C2rot[i], cq, hC2);
            if (i < 15) qrot = dpp_movf<0x121>(qrot);
        }
    }

    const float alpha = 1.f / (1.f + __expf(-alpha0[0]));
    const float p_    = 1.f / (float)S;
    const float fa4   = 40.f * alpha;         // logK = lkP + 40*alpha*tens
    const float c20a  = 20.f * alpha;
    const float qop   = qm * (float)S;        // q/p for folded v-update

    float lkP[5];
    #pragma unroll
    for (int r = 0; r < 5; ++r) {
        float cC = fmaf(npop[r], p_, hC2);    // hC1 + hC2, hC1 = popc/S
        lkP[r] = Mp2g[r] - c20a * cC;         // = -10*(oma*M + 2a*cC)
    }

    // outer 0 analytic: G0 = p q^T => tens0[r] = p * qC2m * popc(msk[r])
    float tens[5], Kt[5], ub[5], v_, G[5];
    {
        float pq = p_ * qC2m;
        #pragma unroll
        for (int r = 0; r < 5; ++r) tens[r] = pq * npop[r];
    }

    for (int o = 1; o <= NOUT; ++o) {
        // K~ = exp(logK - rowmax) (rowmax via DPP)
        #pragma unroll
        for (int r = 0; r < 5; ++r) {
            float lk = fmaf(fa4, tens[r], lkP[r]);
            float rm = rowmax16(act ? lk : NEG);
            Kt[r] = act ? __expf(lk - rm) : 0.f;
        }
        // folded exp-domain Sinkhorn: û = rcp(K~ v); v = (Sq)*rcp(K~^T û)
        v_ = act ? 1.f : 0.f;
        #pragma unroll
        for (int it = 0; it < NSK; ++it) {
            #pragma unroll
            for (int r = 0; r < 5; ++r)
                ub[r] = fast_rcp(rowsum16(Kt[r] * v_));
            float cs = Kt[0]*ub[0] + Kt[1]*ub[1] + Kt[2]*ub[2] + Kt[3]*ub[3];
            cs += (q == 0) ? Kt[4]*ub[4] : 0.f;   // row 16 counted once
            cs += __shfl_xor(cs, 16, 64);
            cs += __shfl_xor(cs, 32, 64);
            v_ = act ? (qop * fast_rcp(cs)) : 0.f; // mask: rcp(0)=inf -> NaN
        }
        float pv = p_ * v_;
        #pragma unroll
        for (int r = 0; r < 5; ++r) G[r] = Kt[r] * ub[r] * pv;

        // H[own rows][m] = sum_k G[s][k]*C2[m][k] via DPP rotation (VALU-only)
        float H[5];
        #pragma unroll
        for (int r = 0; r < 5; ++r) {
            float h = 0.f, Gr = G[r];
            #pragma unroll
            for (int i = 0; i < 16; ++i) {
                h = fmaf(Gr, C2rot[i], h);
                if (i < 15) Gr = dpp_movf<0x121>(Gr);
            }
            H[r] = h;
        }
        // tens[s][m] = sum_{j in mask} H[j][m]
        #pragma unroll
        for (int r = 0; r < 5; ++r) tens[r] = 0.f;
        #pragma unroll
        for (int j = 0; j < 16; ++j) {
            float hj = __shfl(H[j >> 2], ((j & 3) << 4) + m, 64);
            #pragma unroll
            for (int r = 0; r < 5; ++r) tens[r] += ((msk[r] >> j) & 1u) ? hj : 0.f;
        }
        {
            float hj = H[4];   // row 16: replicated locally in every quad
            #pragma unroll
            for (int r = 0; r < 5; ++r) tens[r] += ((msk[r] >> 16) & 1u) ? hj : 0.f;
        }
    }

    // dist = sum G * (-0.1*lkP - a*cC - 2a*tens)
    float val = 0.f;
    #pragma unroll
    for (int r = 0; r < 5; ++r) {
        float cC = fmaf(npop[r], p_, hC2);
        float integ = -0.1f * lkP[r] - alpha * cC - 2.f * alpha * tens[r];
        bool valid = act && (r < 4 || q == 0);
        val += valid ? G[r] * integ : 0.f;
    }
    val = rowsum16(val);
    val += __shfl_xor(val, 16, 64);
    val += __shfl_xor(val, 32, 64);
    if (lane == 0) out[n * T + t] = val;
}

extern "C" void kernel_launch(void* const* d_in, const int* in_sizes, int n_in,
                              void* d_out, int out_size, void* d_ws, size_t ws_size,
                              hipStream_t stream) {
    const float* x      = (const float*)d_in[0];
    const int*   edge   = (const int*)  d_in[1];
    const float* tmpl   = (const float*)d_in[2];
    const float* F2     = (const float*)d_in[3];
    const float* q0     = (const float*)d_in[4];
    const float* alpha0 = (const float*)d_in[5];
    float*       out    = (float*)d_out;

    // ws layout: Mp2 [N*100] f32 | masks [N*17] u32  (~2.34 MB)
    float*    wsMp2  = (float*)d_ws;
    unsigned* wsMask = (unsigned*)((char*)d_ws + (size_t)NN * T * MN * 4);

    hipLaunchKernelGGL(ltfgw_mask, dim3((NN + 3) / 4), dim3(256), 0, stream,
                       edge, wsMask);
    hipLaunchKernelGGL(ltfgw_mp, dim3((NN + TILE_N - 1) / TILE_N), dim3(256), 0, stream,
                       x, F2, alpha0, wsMp2);
    hipLaunchKernelGGL(ltfgw_wave, dim3(NN * 5), dim3(BLOCK), 0, stream,
                       edge, tmpl, q0, alpha0, wsMp2, wsMask, out);
}

// Round 13
// 296.054 us; speedup vs baseline: 1.0772x; 1.0475x over previous
//
#include <hip/hip_runtime.h>
#include <math.h>

#define NN   5000
#define DEG  16
#define S    17
#define T    10
#define MN   10
#define D    128
#define NOUT 3
#define NSK  5

#define WPB   2            // waves per block = templates per block (main)
#define BLOCK (WPB * 64)
#define TILE_N 4           // nodes per block in the Mp GEMM (round-13: was 16)
#define NEG   -3.0e38f

__device__ __forceinline__ float fast_rcp(float x) { return __builtin_amdgcn_rcpf(x); }

// DPP row_ror:k — pure-VALU cross-lane within each 16-lane row.
template <int CTRL>
__device__ __forceinline__ float dpp_movf(float v) {
    return __int_as_float(__builtin_amdgcn_update_dpp(
        0, __float_as_int(v), CTRL, 0xF, 0xF, true));
}
__device__ __forceinline__ int dpp_movi(int v) {
    return __builtin_amdgcn_update_dpp(0, v, 0x121, 0xF, 0xF, true);
}
__device__ __forceinline__ float rowsum16(float v) {
    v += dpp_movf<0x121>(v);
    v += dpp_movf<0x122>(v);
    v += dpp_movf<0x124>(v);
    v += dpp_movf<0x128>(v);
    return v;
}
__device__ __forceinline__ float rowmax16(float v) {
    v = fmaxf(v, dpp_movf<0x121>(v));
    v = fmaxf(v, dpp_movf<0x122>(v));
    v = fmaxf(v, dpp_movf<0x124>(v));
    v = fmaxf(v, dpp_movf<0x128>(v));
    return v;
}

// ---------------- P1: adjacency masks, one WAVE per node (round-10 verified) ----------------
// Rounds 11/12 fused this with the GEMM + template softmax and failed with an
// identical un-located absmax both times -> reverted to this exact passing code.
__global__ __launch_bounds__(256) void ltfgw_mask(
    const int* __restrict__ edge,      // [2, N*DEG]
    unsigned*  __restrict__ wsMask)    // [N, 17]
{
    const int wid  = blockIdx.x * 4 + (threadIdx.x >> 6);
    const int lane = threadIdx.x & 63;
    if (wid >= NN) return;
    const int n = wid;
    const int* dst = edge + NN * DEG;

    const int a = lane >> 2;           // row 0..15
    const int j = lane & 3;            // 4-neighbor chunk

    int locv = 0;                      // lane l<17 holds loc[l]
    if (lane < S) locv = (lane == 0) ? n : dst[n * DEG + lane - 1];
    int loca  = (a == 0) ? n : dst[n * DEG + a - 1];
    int loc16 = dst[n * DEG + DEG - 1];

    const int4* nbp = (const int4*)(dst + (size_t)loca * DEG);
    int4 nb   = nbp[j];
    int  nb16 = (lane < DEG) ? dst[(size_t)loc16 * DEG + lane] : -1;

    unsigned bits = 0, B16 = 0;
    #pragma unroll
    for (int b = 0; b < S; ++b) {
        int lb = __shfl(locv, b, 64);  // literal lane -> v_readlane (sgpr)
        bool hit = (nb.x == lb) | (nb.y == lb) | (nb.z == lb) | (nb.w == lb);
        bits |= hit ? (1u << b) : 0u;
        if (__ballot((lane < DEG) && (nb16 == lb))) B16 |= (1u << b);
    }
    bits |= __shfl_xor(bits, 1, 4);
    bits |= __shfl_xor(bits, 2, 4);

    unsigned g  = __shfl(bits, (lane & 15) * 4, 64);
    unsigned Bl = (lane == 16) ? B16 : g;
    if (lane > 16) Bl = 0;

    unsigned tsel = 0;
    #pragma unroll
    for (int c = 0; c < S; ++c) {
        unsigned long long bal = __ballot((Bl >> c) & 1u);
        unsigned lo = (unsigned)(bal & 0x1FFFFull);
        tsel = (lane == c) ? lo : tsel;
    }

    unsigned maskv = ((Bl | tsel) & ~(1u << lane)) & 0x1FFFFu;
    if (lane < S) wsMask[n * S + lane] = maskv;
}

// ---------------- P2: Mp2[n,c] = -10*(1-a)*(||x[n]||^2 - 2 x[n].F2[c] + ||F2[c]||^2)
// Round-13: round 10's verified arithmetic, re-gridded. Round 10 ran 313
// blocks (~1.2 waves/SIMD -> zero latency hiding -> ~60-75us by gap
// analysis r7/r8/r10). Now TILE_N=4 -> 1250 blocks x 256 threads: 4 nodes
// x 64 col-lanes, 2 cols/thread. xl stride 132 floats = 528 B = 16B-aligned
// (float4-safe; round-11's 129-stride float4 bug class avoided by
// construction). F2 (51.2 KB) is L1/L2-resident after first touch.
__global__ __launch_bounds__(256) void ltfgw_mp(
    const float* __restrict__ x,        // [N, D]
    const float* __restrict__ F2,       // [100, D]
    const float* __restrict__ alpha0,   // [1]
    float*       __restrict__ wsMp2)    // [N, 100]
{
    const int n0  = blockIdx.x * TILE_N;   // 1250*4 = 5000 exact, no guard
    const int tid = threadIdx.x;

    __shared__ float xl[TILE_N][132];

    if (tid < TILE_N * 32) {               // stage 4 x-rows, coalesced
        int nl = tid >> 5, d4 = tid & 31;
        float4 v = ((const float4*)(x + (size_t)(n0 + nl) * D))[d4];
        *(float4*)&xl[nl][d4 * 4] = v;     // 528B row stride: 16B-aligned
    }
    __syncthreads();

    const int nl    = tid >> 6;            // wave = node
    const int cslot = tid & 63;
    const int n     = n0 + nl;
    const int c0    = cslot;
    const int c1    = cslot + 64;
    const bool on1  = (c1 < T * MN);

    const float4* fp0 = (const float4*)(F2 + (size_t)c0 * D);
    const float4* fp1 = (const float4*)(F2 + (size_t)(on1 ? c1 : 0) * D);

    float acc0 = 0.f, acc1 = 0.f, f0 = 0.f, f1 = 0.f, xacc = 0.f;
    for (int d4 = 0; d4 < D / 4; ++d4) {
        float4 xv = *(const float4*)&xl[nl][d4 * 4];   // broadcast (same addr)
        xacc += xv.x*xv.x + xv.y*xv.y + xv.z*xv.z + xv.w*xv.w;
        float4 fa = fp0[d4];
        acc0 += fa.x*xv.x + fa.y*xv.y + fa.z*xv.z + fa.w*xv.w;
        f0   += fa.x*fa.x + fa.y*fa.y + fa.z*fa.z + fa.w*fa.w;
        float4 fb = fp1[d4];
        acc1 += fb.x*xv.x + fb.y*xv.y + fb.z*xv.z + fb.w*xv.w;
        f1   += fb.x*fb.x + fb.y*fb.y + fb.z*fb.z + fb.w*fb.w;
    }

    const float alpha = 1.f / (1.f + __expf(-alpha0[0]));
    const float sc    = -10.f * (1.f - alpha);
    wsMp2[n * (T * MN) + c0] = sc * (xacc - 2.f * acc0 + f0);
    if (on1) wsMp2[n * (T * MN) + c1] = sc * (xacc - 2.f * acc1 + f1);
}

// ---------------- Main: one wave = one (node, template) OT problem ----------------
// EXACT round-10 passing kernel (217us dispatch, VALU-issue-bound,
// VALUBusy ~108%). Lane = q*16+m; lane owns rows s = q+4r (r=0..3) + row 16
// (replicated across quads, counted once). All width-16 reductions via DPP.
// H = G*C2^T via DPP rotation (C2rot probed with the same DPP op ->
// direction-proof). outer-0 tens analytic (G0 = p q^T). Sinkhorn exp-domain
// with per-outer rowmax stabilization; v_ masked on inactive lanes
// (round-4 NaN lesson). __launch_bounds__: block size ONLY (rounds 2-3:
// min-waves hint => allocator snaps + spills GBs).
__global__ __launch_bounds__(BLOCK) void ltfgw_wave(
    const int*      __restrict__ edge,     // [2, N*DEG]
    const float*    __restrict__ tmpl,     // [T, MN, MN]
    const float*    __restrict__ q0,       // [T, MN]
    const float*    __restrict__ alpha0,   // [1]
    const float*    __restrict__ wsMp2,    // [N, 100]
    const unsigned* __restrict__ wsMask,   // [N, 17]
    float*          __restrict__ out)      // [N, T]
{
    const int blk  = blockIdx.x;
    const int n    = blk / 5;
    const int tp   = blk % 5;
    const int tid  = threadIdx.x;
    const int w    = tid >> 6;
    const int t    = tp * 2 + w;
    const int lane = tid & 63;
    const int q    = lane >> 4;
    const int m    = lane & 15;
    const bool act = (m < MN);
    const int mc   = act ? m : (MN - 1);

    __shared__ float C2l[WPB][MN][17];     // stride 17: conflict-free

    const int* dst = edge + NN * DEG;

    // q = softmax(q0[t]) via DPP row reduction (all lanes)
    float vq = q0[t * MN + mc];
    float zq = act ? vq : NEG;
    float mq = rowmax16(zq);
    float sq = rowsum16(__expf(zq - mq));     // inactive: exp(NEG-mq)=0
    const float qm = __expf(vq - (mq + __logf(sq)));   // valid on act lanes
    // C2 = softmax(tmpl, axis=1): active lane m of quad 0 does column m
    if (act && q == 0) {
        float v[MN]; float cm = NEG;
        #pragma unroll
        for (int i = 0; i < MN; ++i) { v[i] = tmpl[t * MN * MN + i * MN + m]; cm = fmaxf(cm, v[i]); }
        float ssum = 0.f;
        #pragma unroll
        for (int i = 0; i < MN; ++i) { v[i] = __expf(v[i] - cm); ssum += v[i]; }
        float inv = 1.f / ssum;
        #pragma unroll
        for (int i = 0; i < MN; ++i) C2l[w][i][m] = v[i] * inv;
    }

    // per-row gathers (L2-resident ws): rows sr[r] = q+4r, clamp 16
    int sr[5];
    #pragma unroll
    for (int r = 0; r < 5; ++r) { int s0 = q + 4 * r; sr[r] = (s0 > 16) ? 16 : s0; }
    unsigned msk[5]; float npop[5]; float Mp2g[5];
    const int cidx = t * MN + mc;
    #pragma unroll
    for (int r = 0; r < 5; ++r) {
        int lr   = (sr[r] == 0) ? n : dst[n * DEG + sr[r] - 1];
        msk[r]   = wsMask[n * S + sr[r]];
        npop[r]  = (float)__popc(msk[r]);
        Mp2g[r]  = wsMp2[lr * (T * MN) + cidx];
    }

    __syncthreads();   // C2l ready

    // C2rot[i] = C2[mc][sigma^i(m)] — sigma probed with the same DPP op,
    // so the rotated-G dot product below is rotation-direction-proof.
    float C2rot[16];
    {
        int li = m;
        #pragma unroll
        for (int i = 0; i < 16; ++i) {
            C2rot[i] = (li < MN) ? C2l[w][mc][li] : 0.f;
            if (i < 15) li = dpp_movi(li);
        }
    }
    // hC2 = sum_j C2[mc][j]^2 q[j]; qC2m = sum_j C2[mc][j] q[j]
    float hC2 = 0.f, qC2m = 0.f;
    {
        float qrot = qm;
        #pragma unroll
        for (int i = 0; i < 16; ++i) {
            float cq = C2rot[i] * qrot;
            qC2m += cq;
            hC2  = fmaf(C2rot[i], cq, hC2);
            if (i < 15) qrot = dpp_movf<0x121>(qrot);
        }
    }

    const float alpha = 1.f / (1.f + __expf(-alpha0[0]));
    const float p_    = 1.f / (float)S;
    const float fa4   = 40.f * alpha;         // logK = lkP + 40*alpha*tens
    const float c20a  = 20.f * alpha;
    const float qop   = qm * (float)S;        // q/p for folded v-update

    float lkP[5];
    #pragma unroll
    for (int r = 0; r < 5; ++r) {
        float cC = fmaf(npop[r], p_, hC2);    // hC1 + hC2, hC1 = popc/S
        lkP[r] = Mp2g[r] - c20a * cC;         // = -10*(oma*M + 2a*cC)
    }

    // outer 0 analytic: G0 = p q^T => tens0[r] = p * qC2m * popc(msk[r])
    float tens[5], Kt[5], ub[5], v_, G[5];
    {
        float pq = p_ * qC2m;
        #pragma unroll
        for (int r = 0; r < 5; ++r) tens[r] = pq * npop[r];
    }

    for (int o = 1; o <= NOUT; ++o) {
        // K~ = exp(logK - rowmax) (rowmax via DPP)
        #pragma unroll
        for (int r = 0; r < 5; ++r) {
            float lk = fmaf(fa4, tens[r], lkP[r]);
            float rm = rowmax16(act ? lk : NEG);
            Kt[r] = act ? __expf(lk - rm) : 0.f;
        }
        // folded exp-domain Sinkhorn: û = rcp(K~ v); v = (Sq)*rcp(K~^T û)
        v_ = act ? 1.f : 0.f;
        #pragma unroll
        for (int it = 0; it < NSK; ++it) {
            #pragma unroll
            for (int r = 0; r < 5; ++r)
                ub[r] = fast_rcp(rowsum16(Kt[r] * v_));
            float cs = Kt[0]*ub[0] + Kt[1]*ub[1] + Kt[2]*ub[2] + Kt[3]*ub[3];
            cs += (q == 0) ? Kt[4]*ub[4] : 0.f;   // row 16 counted once
            cs += __shfl_xor(cs, 16, 64);
            cs += __shfl_xor(cs, 32, 64);
            v_ = act ? (qop * fast_rcp(cs)) : 0.f; // mask: rcp(0)=inf -> NaN
        }
        float pv = p_ * v_;
        #pragma unroll
        for (int r = 0; r < 5; ++r) G[r] = Kt[r] * ub[r] * pv;

        // H[own rows][m] = sum_k G[s][k]*C2[m][k] via DPP rotation (VALU-only)
        float H[5];
        #pragma unroll
        for (int r = 0; r < 5; ++r) {
            float h = 0.f, Gr = G[r];
            #pragma unroll
            for (int i = 0; i < 16; ++i) {
                h = fmaf(Gr, C2rot[i], h);
                if (i < 15) Gr = dpp_movf<0x121>(Gr);
            }
            H[r] = h;
        }
        // tens[s][m] = sum_{j in mask} H[j][m]
        #pragma unroll
        for (int r = 0; r < 5; ++r) tens[r] = 0.f;
        #pragma unroll
        for (int j = 0; j < 16; ++j) {
            float hj = __shfl(H[j >> 2], ((j & 3) << 4) + m, 64);
            #pragma unroll
            for (int r = 0; r < 5; ++r) tens[r] += ((msk[r] >> j) & 1u) ? hj : 0.f;
        }
        {
            float hj = H[4];   // row 16: replicated locally in every quad
            #pragma unroll
            for (int r = 0; r < 5; ++r) tens[r] += ((msk[r] >> 16) & 1u) ? hj : 0.f;
        }
    }

    // dist = sum G * (-0.1*lkP - a*cC - 2a*tens)
    float val = 0.f;
    #pragma unroll
    for (int r = 0; r < 5; ++r) {
        float cC = fmaf(npop[r], p_, hC2);
        float integ = -0.1f * lkP[r] - alpha * cC - 2.f * alpha * tens[r];
        bool valid = act && (r < 4 || q == 0);
        val += valid ? G[r] * integ : 0.f;
    }
    val = rowsum16(val);
    val += __shfl_xor(val, 16, 64);
    val += __shfl_xor(val, 32, 64);
    if (lane == 0) out[n * T + t] = val;
}

extern "C" void kernel_launch(void* const* d_in, const int* in_sizes, int n_in,
                              void* d_out, int out_size, void* d_ws, size_t ws_size,
                              hipStream_t stream) {
    const float* x      = (const float*)d_in[0];
    const int*   edge   = (const int*)  d_in[1];
    const float* tmpl   = (const float*)d_in[2];
    const float* F2     = (const float*)d_in[3];
    const float* q0     = (const float*)d_in[4];
    const float* alpha0 = (const float*)d_in[5];
    float*       out    = (float*)d_out;

    // ws layout: Mp2 [N*100] f32 | masks [N*17] u32  (round-10 exact)
    float*    wsMp2  = (float*)d_ws;
    unsigned* wsMask = (unsigned*)((char*)d_ws + (size_t)NN * T * MN * 4);

    hipLaunchKernelGGL(ltfgw_mask, dim3((NN + 3) / 4), dim3(256), 0, stream,
                       edge, wsMask);
    hipLaunchKernelGGL(ltfgw_mp, dim3(NN / TILE_N), dim3(256), 0, stream,
                       x, F2, alpha0, wsMp2);
    hipLaunchKernelGGL(ltfgw_wave, dim3(NN * 5), dim3(BLOCK), 0, stream,
                       edge, tmpl, q0, alpha0, wsMp2, wsMask, out);
}